// Round 1
// baseline (443.654 us; speedup 1.0000x reference)
//
#include <hip/hip_runtime.h>
#include <hip/hip_bf16.h>

#define D_MODEL 768
#define NSEQ    8192
#define NBATCH  4
#define MROWS   (NBATCH*NSEQ)   // 32768
#define CHUNK   128
#define NCHUNK  (NSEQ/CHUNK)    // 64

typedef __attribute__((ext_vector_type(8))) short bshort8;
typedef __attribute__((ext_vector_type(4))) float f32x4;

__device__ __forceinline__ float bf2f(ushort u){
  union { unsigned int i; float f; } x; x.i = ((unsigned int)u) << 16; return x.f;
}
__device__ __forceinline__ ushort f2bf(float f){
  union { float f; unsigned int i; } x; x.f = f;
  unsigned int r = x.i + 0x7fffu + ((x.i >> 16) & 1u);
  return (ushort)(r >> 16);
}
__device__ __forceinline__ float silu_f(float v){ return v / (1.0f + __expf(-v)); }

__device__ __forceinline__ void async_copy16(const ushort* g, ushort* l){
  __builtin_amdgcn_global_load_lds((const __attribute__((address_space(1))) void*)g,
                                   (__attribute__((address_space(3))) void*)l, 16, 0, 0);
}

// ---------------- weight transpose + bf16 convert: in[R][C] f32 -> out[C][R] bf16
__global__ void tr_cvt(const float* __restrict__ in, ushort* __restrict__ out, int R, int C){
  __shared__ float tile[32][33];
  int c0 = blockIdx.x*32, r0 = blockIdx.y*32;
  int tx = threadIdx.x & 31, ty = threadIdx.x >> 5; // ty 0..7
  #pragma unroll
  for (int p=0;p<4;p++){
    int r = ty + p*8;
    tile[r][tx] = in[(size_t)(r0+r)*C + c0 + tx];
  }
  __syncthreads();
  #pragma unroll
  for (int p=0;p<4;p++){
    int c = ty + p*8;
    out[(size_t)(c0+c)*R + r0 + tx] = f2bf(tile[tx][c]);
  }
}

// ---------------- x fp32 -> bf16
__global__ void cvt_bf16(const float* __restrict__ in, ushort* __restrict__ out, int n){
  int i = (blockIdx.x*256 + threadIdx.x)*4;
  if (i >= n) return;
  const float4 f = *(const float4*)(in + i);
  ushort4 o4; o4.x=f2bf(f.x); o4.y=f2bf(f.y); o4.z=f2bf(f.z); o4.w=f2bf(f.w);
  *(ushort4*)(out + i) = o4;
}

// ---------------- m97-style bf16 GEMM: A[M][K] bf16 row-major, BT[N][K] bf16 row-major.
// MODE 0: N=1536, cols<768 -> xc bf16; cols>=768 -> silu -> z bf16
// MODE 1: N=768, fp32 out
template<int MODE>
__global__ __launch_bounds__(256) void gemm_bt(
    const ushort* __restrict__ A, const ushort* __restrict__ BT,
    ushort* __restrict__ oxc, ushort* __restrict__ oz, float* __restrict__ of,
    int K)
{
  __shared__ __align__(16) ushort Asm[128*32];
  __shared__ __align__(16) ushort Bsm[128*32];
  const int tid = threadIdx.x;
  const int bm = blockIdx.x, bn = blockIdx.y;
  const int lane = tid & 63, wid = tid >> 6;
  const int wm = (wid >> 1) * 64, wn = (wid & 1) * 64;
  const int lm = lane & 15, quad = lane >> 4;

  const ushort* Ag0 = A  + (size_t)(bm*128 +      (tid>>2))*K + (tid&3)*8;
  const ushort* Ag1 = Ag0 + (size_t)64*K;
  const ushort* Bg0 = BT + (size_t)(bn*128 +      (tid>>2))*K + (tid&3)*8;
  const ushort* Bg1 = Bg0 + (size_t)64*K;
  ushort* Al0 = Asm + tid*8;
  ushort* Al1 = Asm + 2048 + tid*8;
  ushort* Bl0 = Bsm + tid*8;
  ushort* Bl1 = Bsm + 2048 + tid*8;

  int ao[4], bo[4];
  #pragma unroll
  for (int i=0;i<4;i++){
    ao[i] = (wm + i*16 + lm)*32 + quad*8;
    bo[i] = (wn + i*16 + lm)*32 + quad*8;
  }

  f32x4 acc[4][4];
  #pragma unroll
  for (int i=0;i<4;i++)
    #pragma unroll
    for (int j=0;j<4;j++) acc[i][j] = (f32x4){0.f,0.f,0.f,0.f};

  const int KT = K >> 5;
  for (int kt=0; kt<KT; ++kt){
    __syncthreads();
    async_copy16(Ag0, Al0); async_copy16(Ag1, Al1);
    async_copy16(Bg0, Bl0); async_copy16(Bg1, Bl1);
    Ag0 += 32; Ag1 += 32; Bg0 += 32; Bg1 += 32;
    asm volatile("s_waitcnt vmcnt(0)" ::: "memory");
    __syncthreads();
    bshort8 av[4], bv[4];
    #pragma unroll
    for (int i=0;i<4;i++){
      av[i] = *(const bshort8*)(Asm + ao[i]);
      bv[i] = *(const bshort8*)(Bsm + bo[i]);
    }
    #pragma unroll
    for (int i=0;i<4;i++)
      #pragma unroll
      for (int j=0;j<4;j++)
        acc[i][j] = __builtin_amdgcn_mfma_f32_16x16x32_bf16(av[i], bv[j], acc[i][j], 0,0,0);
  }

  #pragma unroll
  for (int i=0;i<4;i++){
    int R0 = bm*128 + wm + i*16 + quad*4;
    #pragma unroll
    for (int j=0;j<4;j++){
      int Cc = bn*128 + wn + j*16 + lm;
      #pragma unroll
      for (int r=0;r<4;r++){
        int R = R0 + r;
        float v = acc[i][j][r];
        if (MODE==0){
          if (Cc < 768) oxc[(size_t)R*768 + Cc]       = f2bf(v);
          else          oz [(size_t)R*768 + (Cc-768)] = f2bf(silu_f(v));
        } else {
          of[(size_t)R*768 + Cc] = v;
        }
      }
    }
  }
}

// ---------------- pass 1: conv+silu, per-chunk sums (u never stored)
__global__ void conv_psum(const ushort* __restrict__ xc, const float* __restrict__ cw,
                          const float* __restrict__ cb, float* __restrict__ psum){
  int c = blockIdx.y*64 + threadIdx.x;
  int b = blockIdx.z, ch = blockIdx.x;
  int t0 = ch*CHUNK;
  const ushort* xp = xc + (size_t)b*NSEQ*768 + c;
  float w0=cw[c*3+0], w1=cw[c*3+1], w2=cw[c*3+2], bb=cb[c];
  float xm2 = (t0>=2) ? bf2f(xp[(size_t)(t0-2)*768]) : 0.f;
  float xm1 = (t0>=1) ? bf2f(xp[(size_t)(t0-1)*768]) : 0.f;
  float s = 0.f;
  for (int i=0;i<CHUNK;i++){
    float x0 = bf2f(xp[(size_t)(t0+i)*768]);
    float pre = w0*xm2 + w1*xm1 + w2*x0 + bb;
    s += silu_f(pre);
    xm2 = xm1; xm1 = x0;
  }
  psum[((size_t)b*NCHUNK + ch)*768 + c] = s;
}

// ---------------- pass 2: exclusive scan of chunk sums per (b,c)
__global__ void scan_chunks(const float* __restrict__ psum, float* __restrict__ offs){
  int idx = blockIdx.x*256 + threadIdx.x; // 0..3071
  int b = idx/768, c = idx%768;
  float run = 0.f;
  for (int ch=0; ch<NCHUNK; ch++){
    size_t o = ((size_t)b*NCHUNK + ch)*768 + c;
    offs[o] = run;
    run += psum[o];
  }
}

// ---------------- pass 3: replay conv+silu with carried offset, apply SSM + gate -> v bf16
__global__ void scan_apply(const ushort* __restrict__ xc, const ushort* __restrict__ zb,
                           const float* __restrict__ cw, const float* __restrict__ cb,
                           const float* __restrict__ Bm, const float* __restrict__ Cm,
                           const float* __restrict__ Dv, const float* __restrict__ offs,
                           ushort* __restrict__ v){
  int c = blockIdx.y*64 + threadIdx.x;
  int b = blockIdx.z, ch = blockIdx.x;
  int t0 = ch*CHUNK;
  size_t base = (size_t)b*NSEQ*768 + c;
  const ushort* xp = xc + base;
  const ushort* zp = zb + base;
  ushort* vp = v + base;
  float w0=cw[c*3+0], w1=cw[c*3+1], w2=cw[c*3+2], bb=cb[c];
  float bc = 0.f;
  #pragma unroll
  for (int s=0;s<8;s++) bc += Bm[c*8+s]*Cm[c*8+s];
  float dd = Dv[c];
  float cum = offs[((size_t)b*NCHUNK + ch)*768 + c];
  float xm2 = (t0>=2) ? bf2f(xp[(size_t)(t0-2)*768]) : 0.f;
  float xm1 = (t0>=1) ? bf2f(xp[(size_t)(t0-1)*768]) : 0.f;
  for (int i=0;i<CHUNK;i++){
    size_t o = (size_t)(t0+i)*768;
    float x0 = bf2f(xp[o]);
    float pre = w0*xm2 + w1*xm1 + w2*x0 + bb;
    float u = silu_f(pre);
    cum += u;
    float y = bc*cum + dd*u;
    vp[o] = f2bf(y * bf2f(zp[o]));
    xm2 = xm1; xm1 = x0;
  }
}

extern "C" void kernel_launch(void* const* d_in, const int* in_sizes, int n_in,
                              void* d_out, int out_size, void* d_ws, size_t ws_size,
                              hipStream_t stream)
{
  const float* x      = (const float*)d_in[0];
  const float* W_in   = (const float*)d_in[1];
  const float* conv_w = (const float*)d_in[2];
  const float* conv_b = (const float*)d_in[3];
  const float* Bm     = (const float*)d_in[4];
  const float* Cm     = (const float*)d_in[5];
  const float* Dv     = (const float*)d_in[6];
  const float* W_out  = (const float*)d_in[7];
  float* out = (float*)d_out;

  char* ws = (char*)d_ws;
  // layout (bytes)
  ushort* xbf   = (ushort*)(ws + 0);          // 50331648; reused as v after GEMM1
  ushort* xcbf  = (ushort*)(ws + 50331648);   // 50331648
  ushort* zbf   = (ushort*)(ws + 100663296);  // 50331648
  ushort* wint  = (ushort*)(ws + 150994944);  // 2359296
  ushort* woutt = (ushort*)(ws + 153354240);  // 1179648
  float*  psum  = (float*)(ws + 154533888);   // 786432
  float*  offs  = (float*)(ws + 155320320);   // 786432
  if (ws_size < 156106752) return;            // fail loudly via wrong output

  tr_cvt<<<dim3(1536/32, 768/32), 256, 0, stream>>>(W_in,  wint,  768, 1536);
  tr_cvt<<<dim3(768/32,  768/32), 256, 0, stream>>>(W_out, woutt, 768, 768);
  cvt_bf16<<<(MROWS*768)/1024, 256, 0, stream>>>(x, xbf, MROWS*768);

  gemm_bt<0><<<dim3(MROWS/128, 1536/128), 256, 0, stream>>>(xbf, wint, xcbf, zbf, nullptr, 768);

  conv_psum  <<<dim3(NCHUNK, 12, NBATCH), 64, 0, stream>>>(xcbf, conv_w, conv_b, psum);
  scan_chunks<<<12, 256, 0, stream>>>(psum, offs);
  scan_apply <<<dim3(NCHUNK, 12, NBATCH), 64, 0, stream>>>(xcbf, zbf, conv_w, conv_b,
                                                           Bm, Cm, Dv, offs, xbf /*v*/);

  gemm_bt<1><<<dim3(MROWS/128, 768/128), 256, 0, stream>>>(xbf, woutt, nullptr, nullptr, out, 768);
}

// Round 2
// 410.372 us; speedup vs baseline: 1.0811x; 1.0811x over previous
//
#include <hip/hip_runtime.h>
#include <hip/hip_bf16.h>

#define D_MODEL 768
#define NSEQ    8192
#define NBATCH  4
#define MROWS   (NBATCH*NSEQ)   // 32768
#define CHUNK   128
#define NCHUNK  (NSEQ/CHUNK)    // 64

typedef __attribute__((ext_vector_type(8)))  short bshort8;
typedef __attribute__((ext_vector_type(16))) float f32x16;

__device__ __forceinline__ float bf2f(ushort u){
  union { unsigned int i; float f; } x; x.i = ((unsigned int)u) << 16; return x.f;
}
__device__ __forceinline__ ushort f2bf(float f){
  union { float f; unsigned int i; } x; x.f = f;
  unsigned int r = x.i + 0x7fffu + ((x.i >> 16) & 1u);
  return (ushort)(r >> 16);
}
__device__ __forceinline__ float silu_f(float v){ return v / (1.0f + __expf(-v)); }

__device__ __forceinline__ void async_copy16(const ushort* g, ushort* l){
  __builtin_amdgcn_global_load_lds((const __attribute__((address_space(1))) void*)g,
                                   (__attribute__((address_space(3))) void*)l, 16, 0, 0);
}

// ---------------- weight transpose + bf16 convert: in[R][C] f32 -> out[C][R] bf16
__global__ void tr_cvt(const float* __restrict__ in, ushort* __restrict__ out, int R, int C){
  __shared__ float tile[32][33];
  int c0 = blockIdx.x*32, r0 = blockIdx.y*32;
  int tx = threadIdx.x & 31, ty = threadIdx.x >> 5; // ty 0..7
  #pragma unroll
  for (int p=0;p<4;p++){
    int r = ty + p*8;
    tile[r][tx] = in[(size_t)(r0+r)*C + c0 + tx];
  }
  __syncthreads();
  #pragma unroll
  for (int p=0;p<4;p++){
    int c = ty + p*8;
    out[(size_t)(c0+c)*R + r0 + tx] = f2bf(tile[tx][c]);
  }
}

// ---------------- x fp32 -> bf16
__global__ void cvt_bf16(const float* __restrict__ in, ushort* __restrict__ out, int n){
  int i = (blockIdx.x*256 + threadIdx.x)*4;
  if (i >= n) return;
  const float4 f = *(const float4*)(in + i);
  ushort4 o4; o4.x=f2bf(f.x); o4.y=f2bf(f.y); o4.z=f2bf(f.z); o4.w=f2bf(f.w);
  *(ushort4*)(out + i) = o4;
}

// ---------------- bf16 GEMM, 128x128 tile, BK=64, 32x32x16 MFMA, swizzled LDS.
// A[M][K] bf16 row-major, BT[N][K] bf16 row-major.
// LDS: physical 16B slot p holds logical (row r=p>>3, chunk (p&7)^(r&7)), chunk = 8 ushorts.
// MODE 0: N=1536, cols<768 -> xc bf16; cols>=768 -> silu -> z bf16
// MODE 1: N=768, fp32 out
template<int MODE>
__global__ __launch_bounds__(256) void gemm_bt(
    const ushort* __restrict__ A, const ushort* __restrict__ BT,
    ushort* __restrict__ oxc, ushort* __restrict__ oz, float* __restrict__ of,
    int K)
{
  __shared__ __align__(16) ushort Asm[128*64];
  __shared__ __align__(16) ushort Bsm[128*64];
  const int tid = threadIdx.x;
  const int bm = blockIdx.x, bn = blockIdx.y;
  const int lane = tid & 63, wid = tid >> 6;
  const int wm = (wid >> 1) * 64, wn = (wid & 1) * 64;
  const int l31 = lane & 31, half = lane >> 5;

  // staging: 4 x 16B per thread per matrix, swizzled global source
  const ushort* Ag[4]; const ushort* Bg[4]; ushort* Al[4]; ushort* Bl[4];
  #pragma unroll
  for (int it=0; it<4; ++it){
    int p  = it*256 + tid;
    int r  = p >> 3;
    int cl = (p & 7) ^ (r & 7);
    Ag[it] = A  + (size_t)(bm*128 + r)*K + cl*8;
    Bg[it] = BT + (size_t)(bn*128 + r)*K + cl*8;
    Al[it] = Asm + p*8;
    Bl[it] = Bsm + p*8;
  }

  // read-side row bases
  int arow[2], ar7[2], brow[2], br7[2];
  #pragma unroll
  for (int i=0;i<2;i++){
    int ra = wm + i*32 + l31; arow[i] = ra*64; ar7[i] = ra & 7;
    int rb = wn + i*32 + l31; brow[i] = rb*64; br7[i] = rb & 7;
  }

  f32x16 acc[2][2];
  #pragma unroll
  for (int i=0;i<2;i++)
    #pragma unroll
    for (int j=0;j<2;j++)
      #pragma unroll
      for (int r=0;r<16;r++) acc[i][j][r] = 0.f;

  const int KT = K >> 6;  // BK = 64
  for (int kt=0; kt<KT; ++kt){
    __syncthreads();
    #pragma unroll
    for (int it=0; it<4; ++it){ async_copy16(Ag[it], Al[it]); }
    #pragma unroll
    for (int it=0; it<4; ++it){ async_copy16(Bg[it], Bl[it]); }
    #pragma unroll
    for (int it=0; it<4; ++it){ Ag[it] += 64; Bg[it] += 64; }
    asm volatile("s_waitcnt vmcnt(0)" ::: "memory");
    __syncthreads();

    #pragma unroll
    for (int s=0; s<4; ++s){
      const int cbase = s*2 + half;
      bshort8 av[2], bv[2];
      #pragma unroll
      for (int i=0;i<2;i++){
        av[i] = *(const bshort8*)(Asm + arow[i] + ((cbase ^ ar7[i]) << 3));
        bv[i] = *(const bshort8*)(Bsm + brow[i] + ((cbase ^ br7[i]) << 3));
      }
      acc[0][0] = __builtin_amdgcn_mfma_f32_32x32x16_bf16(av[0], bv[0], acc[0][0], 0,0,0);
      acc[0][1] = __builtin_amdgcn_mfma_f32_32x32x16_bf16(av[0], bv[1], acc[0][1], 0,0,0);
      acc[1][0] = __builtin_amdgcn_mfma_f32_32x32x16_bf16(av[1], bv[0], acc[1][0], 0,0,0);
      acc[1][1] = __builtin_amdgcn_mfma_f32_32x32x16_bf16(av[1], bv[1], acc[1][1], 0,0,0);
    }
  }

  // epilogue: C/D 32x32 layout: col=lane&31, row=(reg&3)+8*(reg>>2)+4*(lane>>5)
  #pragma unroll
  for (int i=0;i<2;i++){
    const int Rbase = bm*128 + wm + i*32 + 4*half;
    #pragma unroll
    for (int j=0;j<2;j++){
      const int Cc = bn*128 + wn + j*32 + l31;
      #pragma unroll
      for (int reg=0; reg<16; reg++){
        const int R = Rbase + (reg & 3) + 8*(reg >> 2);
        const float v = acc[i][j][reg];
        if (MODE==0){
          if (Cc < 768) oxc[(size_t)R*768 + Cc]       = f2bf(v);
          else          oz [(size_t)R*768 + (Cc-768)] = f2bf(silu_f(v));
        } else {
          of[(size_t)R*768 + Cc] = v;
        }
      }
    }
  }
}

// ---------------- pass 1: conv+silu, per-chunk sums (u never stored)
__global__ void conv_psum(const ushort* __restrict__ xc, const float* __restrict__ cw,
                          const float* __restrict__ cb, float* __restrict__ psum){
  int c = blockIdx.y*64 + threadIdx.x;
  int b = blockIdx.z, ch = blockIdx.x;
  int t0 = ch*CHUNK;
  const ushort* xp = xc + (size_t)b*NSEQ*768 + c;
  float w0=cw[c*3+0], w1=cw[c*3+1], w2=cw[c*3+2], bb=cb[c];
  float xm2 = (t0>=2) ? bf2f(xp[(size_t)(t0-2)*768]) : 0.f;
  float xm1 = (t0>=1) ? bf2f(xp[(size_t)(t0-1)*768]) : 0.f;
  float s = 0.f;
  for (int i=0;i<CHUNK;i++){
    float x0 = bf2f(xp[(size_t)(t0+i)*768]);
    float pre = w0*xm2 + w1*xm1 + w2*x0 + bb;
    s += silu_f(pre);
    xm2 = xm1; xm1 = x0;
  }
  psum[((size_t)b*NCHUNK + ch)*768 + c] = s;
}

// ---------------- pass 2: exclusive scan of chunk sums per (b,c)
__global__ void scan_chunks(const float* __restrict__ psum, float* __restrict__ offs){
  int idx = blockIdx.x*256 + threadIdx.x; // 0..3071
  int b = idx/768, c = idx%768;
  float run = 0.f;
  for (int ch=0; ch<NCHUNK; ch++){
    size_t o = ((size_t)b*NCHUNK + ch)*768 + c;
    offs[o] = run;
    run += psum[o];
  }
}

// ---------------- pass 3: replay conv+silu with carried offset, apply SSM + gate -> v bf16
__global__ void scan_apply(const ushort* __restrict__ xc, const ushort* __restrict__ zb,
                           const float* __restrict__ cw, const float* __restrict__ cb,
                           const float* __restrict__ Bm, const float* __restrict__ Cm,
                           const float* __restrict__ Dv, const float* __restrict__ offs,
                           ushort* __restrict__ v){
  int c = blockIdx.y*64 + threadIdx.x;
  int b = blockIdx.z, ch = blockIdx.x;
  int t0 = ch*CHUNK;
  size_t base = (size_t)b*NSEQ*768 + c;
  const ushort* xp = xc + base;
  const ushort* zp = zb + base;
  ushort* vp = v + base;
  float w0=cw[c*3+0], w1=cw[c*3+1], w2=cw[c*3+2], bb=cb[c];
  float bc = 0.f;
  #pragma unroll
  for (int s=0;s<8;s++) bc += Bm[c*8+s]*Cm[c*8+s];
  float dd = Dv[c];
  float cum = offs[((size_t)b*NCHUNK + ch)*768 + c];
  float xm2 = (t0>=2) ? bf2f(xp[(size_t)(t0-2)*768]) : 0.f;
  float xm1 = (t0>=1) ? bf2f(xp[(size_t)(t0-1)*768]) : 0.f;
  for (int i=0;i<CHUNK;i++){
    size_t o = (size_t)(t0+i)*768;
    float x0 = bf2f(xp[o]);
    float pre = w0*xm2 + w1*xm1 + w2*x0 + bb;
    float u = silu_f(pre);
    cum += u;
    float y = bc*cum + dd*u;
    vp[o] = f2bf(y * bf2f(zp[o]));
    xm2 = xm1; xm1 = x0;
  }
}

extern "C" void kernel_launch(void* const* d_in, const int* in_sizes, int n_in,
                              void* d_out, int out_size, void* d_ws, size_t ws_size,
                              hipStream_t stream)
{
  const float* x      = (const float*)d_in[0];
  const float* W_in   = (const float*)d_in[1];
  const float* conv_w = (const float*)d_in[2];
  const float* conv_b = (const float*)d_in[3];
  const float* Bm     = (const float*)d_in[4];
  const float* Cm     = (const float*)d_in[5];
  const float* Dv     = (const float*)d_in[6];
  const float* W_out  = (const float*)d_in[7];
  float* out = (float*)d_out;

  char* ws = (char*)d_ws;
  ushort* xbf   = (ushort*)(ws + 0);          // 50331648; reused as v after GEMM1
  ushort* xcbf  = (ushort*)(ws + 50331648);   // 50331648
  ushort* zbf   = (ushort*)(ws + 100663296);  // 50331648
  ushort* wint  = (ushort*)(ws + 150994944);  // 2359296
  ushort* woutt = (ushort*)(ws + 153354240);  // 1179648
  float*  psum  = (float*)(ws + 154533888);   // 786432
  float*  offs  = (float*)(ws + 155320320);   // 786432
  if (ws_size < 156106752) return;

  tr_cvt<<<dim3(1536/32, 768/32), 256, 0, stream>>>(W_in,  wint,  768, 1536);
  tr_cvt<<<dim3(768/32,  768/32), 256, 0, stream>>>(W_out, woutt, 768, 768);
  cvt_bf16<<<(MROWS*768)/1024, 256, 0, stream>>>(x, xbf, MROWS*768);

  gemm_bt<0><<<dim3(MROWS/128, 1536/128), 256, 0, stream>>>(xbf, wint, xcbf, zbf, nullptr, 768);

  conv_psum  <<<dim3(NCHUNK, 12, NBATCH), 64, 0, stream>>>(xcbf, conv_w, conv_b, psum);
  scan_chunks<<<12, 256, 0, stream>>>(psum, offs);
  scan_apply <<<dim3(NCHUNK, 12, NBATCH), 64, 0, stream>>>(xcbf, zbf, conv_w, conv_b,
                                                           Bm, Cm, Dv, offs, xbf /*v*/);

  gemm_bt<1><<<dim3(MROWS/128, 768/128), 256, 0, stream>>>(xbf, woutt, nullptr, nullptr, out, 768);
}